// Round 1
// baseline (1457.402 us; speedup 1.0000x reference)
//
#include <hip/hip_runtime.h>
#include <math.h>

// ---------------------------------------------------------------------------
// CrossGroupedQueryAttention on MI355X — round 1 (correctness-first, MFMA GEMMs)
//
// Pipeline:
//  k0_prep     : fold LN gamma into w_q/w_kv (bf16), rowsums, biases, w_out->bf16
//  k1_stats    : per-pixel LN mean/rstd for q,k  +  transpose to qt/kt [b][p][384] bf16
//  gemm_bt<0>  : qp  = LNfold-GEMM(w_q',  qt)   [b][384][hw] bf16
//  gemm_bt<0>  : kvp = LNfold-GEMM(w_kv', kt)   [b][192][hw] bf16
//  k4_dw       : depthwise 3x3 (zero pad) -> qd, kvd (bf16, [c][p] layout)
//  k5_norm     : 1/max(||row||,eps) for q rows (384/b) and k rows (96/b)
//  k5b_vt      : transpose v rows (kvd[96..191]) -> vt [b][p][96] bf16
//  k6_qk       : split-K QK^T partials (deterministic, no atomics)
//  k7_sm       : reduce partials, apply norms*temperature, softmax, write P~ [b][384][96]
//  k8_pv       : Yt[p][c] = sum_dk vt[p,dk] * P~[c,dk]   (GQA via zero-padded P~)
//  gemm_bt<1>  : out = w_out' x Yt  (f32, NCHW)
// ---------------------------------------------------------------------------

typedef unsigned short u16;
typedef unsigned int u32;
typedef short s16x8 __attribute__((ext_vector_type(8)));
typedef float f32x4 __attribute__((ext_vector_type(4)));

#define HW 16384
#define NB 8
#define CDIM 384
#define KVC 192

__device__ __forceinline__ float b2f(u16 u) {
  return __uint_as_float(((u32)u) << 16);
}
__device__ __forceinline__ u16 f2b(float f) {
  u32 u = __float_as_uint(f);
  u += 0x7fffu + ((u >> 16) & 1u);   // RNE
  return (u16)(u >> 16);
}

// ---------------------------------------------------------------------------
// k0: fold LN weights into conv weights.  1024 threads.
//  rows 0..383   : w_q'  = bf16(w_q * lnq_w); rowsum, bias
//  rows 384..639 : w_kv' (rows 192..255 zero pad); rowsum, bias
//  rows 640..1023: w_out -> bf16
// ---------------------------------------------------------------------------
__global__ void k0_prep(const float* __restrict__ wq, const float* __restrict__ wkv,
                        const float* __restrict__ wo,
                        const float* __restrict__ lnqw, const float* __restrict__ lnqb,
                        const float* __restrict__ lnkw, const float* __restrict__ lnkb,
                        u16* __restrict__ wqp, float* __restrict__ rwsQ, float* __restrict__ biasQ,
                        u16* __restrict__ wkvp, float* __restrict__ rwsKV, float* __restrict__ biasKV,
                        u16* __restrict__ wop) {
  int r = blockIdx.x * 256 + threadIdx.x;
  if (r < 384) {
    float rs = 0.f, bs = 0.f;
    for (int i = 0; i < 384; ++i) {
      float wp = wq[r * 384 + i] * lnqw[i];
      u16 h = f2b(wp);
      rs += b2f(h);
      bs += wq[r * 384 + i] * lnqb[i];
      wqp[r * 384 + i] = h;
    }
    rwsQ[r] = rs; biasQ[r] = bs;
  } else if (r < 640) {
    int o = r - 384;
    if (o < 192) {
      float rs = 0.f, bs = 0.f;
      for (int i = 0; i < 384; ++i) {
        float wp = wkv[o * 384 + i] * lnkw[i];
        u16 h = f2b(wp);
        rs += b2f(h);
        bs += wkv[o * 384 + i] * lnkb[i];
        wkvp[o * 384 + i] = h;
      }
      rwsKV[o] = rs; biasKV[o] = bs;
    } else {
      for (int i = 0; i < 384; ++i) wkvp[o * 384 + i] = 0;
      rwsKV[o] = 0.f; biasKV[o] = 0.f;
    }
  } else {
    int o = r - 640;
    for (int i = 0; i < 384; ++i) wop[o * 384 + i] = f2b(wo[o * 384 + i]);
  }
}

// ---------------------------------------------------------------------------
// k1: LN stats per pixel + transpose f32 [c][p] -> bf16 [p][c].
// grid (64, 8, 2): x = p-block, y = b, z = tensor (0=q,1=k). 256 thr.
// ---------------------------------------------------------------------------
__global__ void k1_stats(const float* __restrict__ q, const float* __restrict__ k,
                         u16* __restrict__ qt, u16* __restrict__ kt,
                         float* __restrict__ muQ, float* __restrict__ sdQ,
                         float* __restrict__ muK, float* __restrict__ sdK) {
  int p = blockIdx.x * 256 + threadIdx.x;     // 0..16383
  int b = blockIdx.y;
  int t = blockIdx.z;
  const float* src = t ? k : q;
  u16* dst = t ? kt : qt;
  float* mu = t ? muK : muQ;
  float* sd = t ? sdK : sdQ;

  size_t sbase = ((size_t)b * CDIM) * HW + p;
  uint4* dv = (uint4*)dst;
  size_t drow = ((size_t)(b * HW + p)) * 48;   // in uint4 (8 bf16) units
  float sum = 0.f, sq = 0.f;
  for (int c8 = 0; c8 < 48; ++c8) {
    u32 w[4];
#pragma unroll
    for (int j = 0; j < 8; ++j) {
      float v = src[sbase + (size_t)(c8 * 8 + j) * HW];
      sum += v; sq += v * v;
      u16 h = f2b(v);
      if (j & 1) w[j >> 1] |= ((u32)h) << 16; else w[j >> 1] = (u32)h;
    }
    dv[drow + c8] = make_uint4(w[0], w[1], w[2], w[3]);
  }
  float m = sum * (1.f / 384.f);
  float var = sq * (1.f / 384.f) - m * m;
  int idx = b * HW + p;
  mu[idx] = m;
  sd[idx] = rsqrtf(var + 1e-5f);
}

// ---------------------------------------------------------------------------
// BT-GEMM: D[o][p] = sum_k A[o][k] * Bt[p][k], K=384.
// Block 256 thr (4 waves 2x2), tile 128x128, frags direct from global.
// MODE 0: LN epilogue, bf16 out [b][M][hw].  MODE 1: plain f32 out [b][384][hw].
// ---------------------------------------------------------------------------
template <int MODE>
__global__ __launch_bounds__(256) void gemm_bt(const u16* __restrict__ A,
                                               const u16* __restrict__ Bt,
                                               const float* __restrict__ rowsum,
                                               const float* __restrict__ bias,
                                               const float* __restrict__ mu,
                                               const float* __restrict__ rstd,
                                               void* __restrict__ outv, int M) {
  int b = blockIdx.z, ot = blockIdx.y, pt = blockIdx.x;
  int tid = threadIdx.x;
  int w = tid >> 6, l = tid & 63;
  int wm = w >> 1, wn = w & 1;
  int lr = l & 15, lg = l >> 4;

  f32x4 acc[4][4] = {};
  int arow0 = ot * 128 + wm * 64 + lr;
  size_t brow0 = (size_t)(b * HW + pt * 128 + wn * 64 + lr);

  for (int ks = 0; ks < 12; ++ks) {
    int ko = ks * 32 + lg * 8;
    s16x8 a[4], bb[4];
#pragma unroll
    for (int mf = 0; mf < 4; ++mf)
      a[mf] = *(const s16x8*)(A + (size_t)(arow0 + mf * 16) * 384 + ko);
#pragma unroll
    for (int nf = 0; nf < 4; ++nf)
      bb[nf] = *(const s16x8*)(Bt + (brow0 + nf * 16) * 384 + ko);
#pragma unroll
    for (int mf = 0; mf < 4; ++mf)
#pragma unroll
      for (int nf = 0; nf < 4; ++nf)
        acc[mf][nf] = __builtin_amdgcn_mfma_f32_16x16x32_bf16(a[mf], bb[nf], acc[mf][nf], 0, 0, 0);
  }

#pragma unroll
  for (int nf = 0; nf < 4; ++nf) {
    int p = pt * 128 + wn * 64 + nf * 16 + lr;
    float m_ = 0.f, s_ = 0.f;
    if (MODE == 0) { int pi = b * HW + p; m_ = mu[pi]; s_ = rstd[pi]; }
#pragma unroll
    for (int mf = 0; mf < 4; ++mf) {
#pragma unroll
      for (int r = 0; r < 4; ++r) {
        int o = ot * 128 + wm * 64 + mf * 16 + lg * 4 + r;
        if (MODE == 0) {
          if (o < M) {
            float v = s_ * (acc[mf][nf][r] - m_ * rowsum[o]) + bias[o];
            ((u16*)outv)[((size_t)(b * M + o)) * HW + p] = f2b(v);
          }
        } else {
          ((float*)outv)[((size_t)(b * CDIM + o)) * HW + p] = acc[mf][nf][r];
        }
      }
    }
  }
}

// ---------------------------------------------------------------------------
// k4: depthwise 3x3, zero pad. grid (576, 8): x = channel (0..383 q, 384..575 kv)
// ---------------------------------------------------------------------------
__global__ void k4_dw(const u16* __restrict__ qp, const u16* __restrict__ kvp,
                      const float* __restrict__ wqdw, const float* __restrict__ wkvdw,
                      u16* __restrict__ qd, u16* __restrict__ kvd) {
  int c = blockIdx.x, b = blockIdx.y;
  const u16* in; u16* outb; const float* wp; int C;
  if (c < 384) { in = qp; outb = qd; wp = wqdw + c * 9; C = CDIM; }
  else { c -= 384; in = kvp; outb = kvd; wp = wkvdw + c * 9; C = KVC; }
  size_t base = ((size_t)(b * C + c)) * HW;
  float w[9];
#pragma unroll
  for (int j = 0; j < 9; ++j) w[j] = wp[j];

  for (int idx = threadIdx.x; idx < HW; idx += 256) {
    int y = idx >> 7, x = idx & 127;
    float a = 0.f;
#pragma unroll
    for (int ky = 0; ky < 3; ++ky) {
      int yy = y + ky - 1;
      if ((unsigned)yy < 128u) {
#pragma unroll
        for (int kx = 0; kx < 3; ++kx) {
          int xx = x + kx - 1;
          if ((unsigned)xx < 128u) a += w[ky * 3 + kx] * b2f(in[base + yy * 128 + xx]);
        }
      }
    }
    outb[base + idx] = f2b(a);
  }
}

// ---------------------------------------------------------------------------
// k5: row l2 norms. grid (480, 8): x<384 -> qd row, else kvd k-row (0..95).
// ---------------------------------------------------------------------------
__global__ void k5_norm(const u16* __restrict__ qd, const u16* __restrict__ kvd,
                        float* __restrict__ rnq, float* __restrict__ rnk) {
  int row = blockIdx.x, b = blockIdx.y, tid = threadIdx.x;
  const u16* src; float* dst;
  if (row < 384) { src = qd + ((size_t)(b * CDIM + row)) * HW; dst = rnq + b * 384 + row; }
  else { int rr = row - 384; src = kvd + ((size_t)(b * KVC + rr)) * HW; dst = rnk + b * 96 + rr; }
  const uint4* sv = (const uint4*)src;   // 2048 uint4 per row
  float s = 0.f;
  for (int e = tid; e < 2048; e += 256) {
    uint4 v = sv[e];
    u32 ws[4] = {v.x, v.y, v.z, v.w};
#pragma unroll
    for (int j = 0; j < 4; ++j) {
      float a = b2f((u16)(ws[j] & 0xffff)), c = b2f((u16)(ws[j] >> 16));
      s += a * a + c * c;
    }
  }
  __shared__ float red[256];
  red[tid] = s; __syncthreads();
  for (int st = 128; st > 0; st >>= 1) { if (tid < st) red[tid] += red[tid + st]; __syncthreads(); }
  if (tid == 0) { float n = sqrtf(red[0]); *dst = 1.f / fmaxf(n, 1e-12f); }
}

// ---------------------------------------------------------------------------
// k5b: transpose v (kvd rows 96..191) -> vt [b][p][96] bf16. grid (64, 8).
// ---------------------------------------------------------------------------
__global__ void k5b_vt(const u16* __restrict__ kvd, u16* __restrict__ vt) {
  int p = blockIdx.x * 256 + threadIdx.x;
  int b = blockIdx.y;
  size_t sb = ((size_t)(b * KVC + 96)) * HW + p;
  uint4* dv = (uint4*)vt + ((size_t)(b * HW + p)) * 12;
  for (int j8 = 0; j8 < 12; ++j8) {
    u32 w[4];
#pragma unroll
    for (int j = 0; j < 8; ++j) {
      u16 h = kvd[sb + (size_t)(j8 * 8 + j) * HW];
      if (j & 1) w[j >> 1] |= ((u32)h) << 16; else w[j >> 1] = (u32)h;
    }
    dv[j8] = make_uint4(w[0], w[1], w[2], w[3]);
  }
}

// ---------------------------------------------------------------------------
// k6: split-K QK^T partials. grid (16, 8, 8): x = kchunk(1024), y = head, z = b.
// 4 waves; wave handles its own 256-px subchunk; writes its own 48x48 partial.
// ---------------------------------------------------------------------------
__global__ __launch_bounds__(256) void k6_qk(const u16* __restrict__ qd,
                                             const u16* __restrict__ kvd,
                                             float* __restrict__ spart) {
  int kc = blockIdx.x, h = blockIdx.y, b = blockIdx.z;
  int tid = threadIdx.x;
  int w = tid >> 6, l = tid & 63, lr = l & 15, lg = l >> 4;
  int g = h >> 2;
  int p0 = kc * 1024 + w * 256;

  f32x4 acc[3][3] = {};
  size_t qbase = ((size_t)(b * CDIM + h * 48 + lr)) * HW;
  size_t kbase = ((size_t)(b * KVC + g * 48 + lr)) * HW;

  for (int ks = 0; ks < 8; ++ks) {
    int pp = p0 + ks * 32 + lg * 8;
    s16x8 a[3], bb[3];
#pragma unroll
    for (int mi = 0; mi < 3; ++mi) a[mi] = *(const s16x8*)(qd + qbase + (size_t)mi * 16 * HW + pp);
#pragma unroll
    for (int ni = 0; ni < 3; ++ni) bb[ni] = *(const s16x8*)(kvd + kbase + (size_t)ni * 16 * HW + pp);
#pragma unroll
    for (int mi = 0; mi < 3; ++mi)
#pragma unroll
      for (int ni = 0; ni < 3; ++ni)
        acc[mi][ni] = __builtin_amdgcn_mfma_f32_16x16x32_bf16(a[mi], bb[ni], acc[mi][ni], 0, 0, 0);
  }

  size_t sb = ((size_t)((((b * 8 + h) * 16) + kc) * 4 + w)) * 2304;
#pragma unroll
  for (int mi = 0; mi < 3; ++mi)
#pragma unroll
    for (int ni = 0; ni < 3; ++ni)
#pragma unroll
      for (int r = 0; r < 4; ++r) {
        int c = mi * 16 + lg * 4 + r, d = ni * 16 + lr;
        spart[sb + c * 48 + d] = acc[mi][ni][r];
      }
}

// ---------------------------------------------------------------------------
// k7: reduce partials + scale + softmax -> P~ [b][384][96] bf16 (zero off-group).
// grid (8, 8): x = head, y = b. 64 threads.
// ---------------------------------------------------------------------------
__global__ void k7_sm(const float* __restrict__ spart, const float* __restrict__ temp,
                      const float* __restrict__ rnq, const float* __restrict__ rnk,
                      u16* __restrict__ ptil) {
  int h = blockIdx.x, b = blockIdx.y, tid = threadIdx.x;
  int g = h >> 2;
  __shared__ float S[2304];
  size_t base = ((size_t)((b * 8 + h) * 64)) * 2304;
  for (int e = tid; e < 2304; e += 64) {
    float s = 0.f;
    for (int j = 0; j < 64; ++j) s += spart[base + (size_t)j * 2304 + e];
    S[e] = s;
  }
  __syncthreads();
  if (tid < 48) {
    int c = tid;
    float sq = temp[h] * rnq[b * 384 + h * 48 + c];
    float mx = -1e30f;
    for (int d = 0; d < 48; ++d) {
      float v = S[c * 48 + d] * sq * rnk[b * 96 + g * 48 + d];
      mx = fmaxf(mx, v);
    }
    float sum = 0.f;
    for (int d = 0; d < 48; ++d) {
      float v = S[c * 48 + d] * sq * rnk[b * 96 + g * 48 + d];
      sum += __expf(v - mx);
    }
    float inv = 1.f / sum;
    u16* row = ptil + ((size_t)(b * 384 + h * 48 + c)) * 96;
    for (int dk = 0; dk < 96; ++dk) {
      int d = dk - g * 48;
      float pv = 0.f;
      if (d >= 0 && d < 48) {
        float v = S[c * 48 + d] * sq * rnk[b * 96 + g * 48 + d];
        pv = __expf(v - mx) * inv;
      }
      row[dk] = f2b(pv);
    }
  }
}

// ---------------------------------------------------------------------------
// k8: Yt[p][c] = sum_dk vt[p][dk] * P~[c][dk].  grid (128, 8), 512 thr (8 waves 2x4).
// D rows = p (so the write IS the transpose the final GEMM needs).
// ---------------------------------------------------------------------------
__global__ __launch_bounds__(512) void k8_pv(const u16* __restrict__ vt,
                                             const u16* __restrict__ ptil,
                                             u16* __restrict__ yt) {
  int ptb = blockIdx.x, b = blockIdx.y;
  int tid = threadIdx.x;
  int w = tid >> 6, l = tid & 63, lr = l & 15, lg = l >> 4;
  int wm = w >> 2, wn = w & 3;

  f32x4 acc[4][6] = {};
  size_t arow0 = ((size_t)(b * HW + ptb * 128 + wm * 64 + lr)) * 96;
  size_t brow0 = ((size_t)(b * CDIM + wn * 96 + lr)) * 96;

  for (int ks = 0; ks < 3; ++ks) {
    int ko = ks * 32 + lg * 8;
    s16x8 a[4], bb[6];
#pragma unroll
    for (int mf = 0; mf < 4; ++mf) a[mf] = *(const s16x8*)(vt + arow0 + (size_t)mf * 16 * 96 + ko);
#pragma unroll
    for (int nf = 0; nf < 6; ++nf) bb[nf] = *(const s16x8*)(ptil + brow0 + (size_t)nf * 16 * 96 + ko);
#pragma unroll
    for (int mf = 0; mf < 4; ++mf)
#pragma unroll
      for (int nf = 0; nf < 6; ++nf)
        acc[mf][nf] = __builtin_amdgcn_mfma_f32_16x16x32_bf16(a[mf], bb[nf], acc[mf][nf], 0, 0, 0);
  }

#pragma unroll
  for (int mf = 0; mf < 4; ++mf)
#pragma unroll
    for (int nf = 0; nf < 6; ++nf)
#pragma unroll
      for (int r = 0; r < 4; ++r) {
        int p = ptb * 128 + wm * 64 + mf * 16 + lg * 4 + r;
        int c = wn * 96 + nf * 16 + lr;
        yt[((size_t)(b * HW + p)) * 384 + c] = f2b(acc[mf][nf][r]);
      }
}

// ---------------------------------------------------------------------------
extern "C" void kernel_launch(void* const* d_in, const int* in_sizes, int n_in,
                              void* d_out, int out_size, void* d_ws, size_t ws_size,
                              hipStream_t stream) {
  const float* q    = (const float*)d_in[0];
  const float* k    = (const float*)d_in[1];
  const float* w_q  = (const float*)d_in[2];
  const float* w_kv = (const float*)d_in[3];
  const float* w_qd = (const float*)d_in[4];
  const float* w_kd = (const float*)d_in[5];
  const float* w_o  = (const float*)d_in[6];
  const float* temp = (const float*)d_in[7];
  const float* lnqw = (const float*)d_in[8];
  const float* lnqb = (const float*)d_in[9];
  const float* lnkw = (const float*)d_in[10];
  const float* lnkb = (const float*)d_in[11];
  float* out = (float*)d_out;

  char* ws = (char*)d_ws;
  size_t off = 0;
  auto alloc = [&](size_t bytes) -> void* {
    void* p = ws + off;
    off += (bytes + 255) & ~(size_t)255;
    return p;
  };

  u16*   wqp   = (u16*)alloc(384 * 384 * 2);
  float* rwsQ  = (float*)alloc(384 * 4);
  float* biasQ = (float*)alloc(384 * 4);
  u16*   wkvp  = (u16*)alloc(256 * 384 * 2);   // padded to 256 rows
  float* rwsKV = (float*)alloc(256 * 4);
  float* biasKV= (float*)alloc(256 * 4);
  u16*   wop   = (u16*)alloc(384 * 384 * 2);
  float* muQ   = (float*)alloc((size_t)NB * HW * 4);
  float* sdQ   = (float*)alloc((size_t)NB * HW * 4);
  float* muK   = (float*)alloc((size_t)NB * HW * 4);
  float* sdK   = (float*)alloc((size_t)NB * HW * 4);
  u16*   qt    = (u16*)alloc((size_t)NB * HW * CDIM * 2);  // aliased as qd later
  u16*   kt    = (u16*)alloc((size_t)NB * HW * CDIM * 2);  // aliased as kvd later
  u16*   qp    = (u16*)alloc((size_t)NB * CDIM * HW * 2);  // aliased as yt later
  u16*   kvp   = (u16*)alloc((size_t)NB * KVC * HW * 2);
  u16*   vt    = (u16*)alloc((size_t)NB * HW * 96 * 2);
  float* spart = (float*)alloc((size_t)4096 * 2304 * 4);
  u16*   ptil  = (u16*)alloc((size_t)NB * CDIM * 96 * 2);
  float* rnq   = (float*)alloc((size_t)NB * 384 * 4);
  float* rnk   = (float*)alloc((size_t)NB * 96 * 4);

  // lifetime aliases (sequential stream => safe)
  u16* qd  = qt;    // qt dead after gemm q; qd written by k4
  u16* kvd = kt;    // kt dead after gemm kv
  u16* yt  = qp;    // qp dead after k4

  k0_prep<<<4, 256, 0, stream>>>(w_q, w_kv, w_o, lnqw, lnqb, lnkw, lnkb,
                                 wqp, rwsQ, biasQ, wkvp, rwsKV, biasKV, wop);

  k1_stats<<<dim3(64, NB, 2), 256, 0, stream>>>(q, k, qt, kt, muQ, sdQ, muK, sdK);

  gemm_bt<0><<<dim3(128, 3, NB), 256, 0, stream>>>(wqp, qt, rwsQ, biasQ, muQ, sdQ, qp, 384);
  gemm_bt<0><<<dim3(128, 2, NB), 256, 0, stream>>>(wkvp, kt, rwsKV, biasKV, muK, sdK, kvp, 192);

  k4_dw<<<dim3(576, NB), 256, 0, stream>>>(qp, kvp, w_qd, w_kd, qd, kvd);

  k5_norm<<<dim3(480, NB), 256, 0, stream>>>(qd, kvd, rnq, rnk);
  k5b_vt<<<dim3(64, NB), 256, 0, stream>>>(kvd, vt);

  k6_qk<<<dim3(16, 8, NB), 256, 0, stream>>>(qd, kvd, spart);
  k7_sm<<<dim3(8, NB), 64, 0, stream>>>(spart, temp, rnq, rnk, ptil);

  k8_pv<<<dim3(128, NB), 512, 0, stream>>>(vt, ptil, yt);

  gemm_bt<1><<<dim3(128, 3, NB), 256, 0, stream>>>(wop, yt, nullptr, nullptr, nullptr, nullptr, out, 384);
}

// Round 2
// 1025.218 us; speedup vs baseline: 1.4216x; 1.4216x over previous
//
#include <hip/hip_runtime.h>
#include <math.h>

// ---------------------------------------------------------------------------
// CrossGroupedQueryAttention on MI355X — round 2
//
// R1 post-mortem: k4_dw (scalar-u16-load depthwise conv) was 500us/1457us,
// latency-bound (HBM 5.6%, VALU 18%). This round: LDS-staged plane version
// with vectorized loads/stores + fused l2norm row reduction (k5_norm deleted).
//
// Pipeline:
//  k0_prep     : fold LN gamma into w_q/w_kv (bf16), rowsums, biases, w_out->bf16
//  k1_stats    : per-pixel LN mean/rstd for q,k  +  transpose to qt/kt [b][p][384] bf16
//  gemm_bt<0>  : qp  = LNfold-GEMM(w_q',  qt)   [b][384][hw] bf16
//  gemm_bt<0>  : kvp = LNfold-GEMM(w_kv', kt)   [b][192][hw] bf16
//  k4_dw       : depthwise 3x3 (LDS-staged plane) -> qd, kvd  + fused row l2norms
//  k5b_vt      : transpose v rows (kvd[96..191]) -> vt [b][p][96] bf16
//  k6_qk       : split-K QK^T partials (deterministic, no atomics)
//  k7_sm       : reduce partials, apply norms*temperature, softmax, write P~ [b][384][96]
//  k8_pv       : Yt[p][c] = sum_dk vt[p,dk] * P~[c,dk]   (GQA via zero-padded P~)
//  gemm_bt<1>  : out = w_out' x Yt  (f32, NCHW)
// ---------------------------------------------------------------------------

typedef unsigned short u16;
typedef unsigned int u32;
typedef short s16x8 __attribute__((ext_vector_type(8)));
typedef float f32x4 __attribute__((ext_vector_type(4)));

#define HW 16384
#define NB 8
#define CDIM 384
#define KVC 192

__device__ __forceinline__ float b2f(u16 u) {
  return __uint_as_float(((u32)u) << 16);
}
__device__ __forceinline__ u16 f2b(float f) {
  u32 u = __float_as_uint(f);
  u += 0x7fffu + ((u >> 16) & 1u);   // RNE
  return (u16)(u >> 16);
}

// ---------------------------------------------------------------------------
// k0: fold LN weights into conv weights.  1024 threads.
// ---------------------------------------------------------------------------
__global__ void k0_prep(const float* __restrict__ wq, const float* __restrict__ wkv,
                        const float* __restrict__ wo,
                        const float* __restrict__ lnqw, const float* __restrict__ lnqb,
                        const float* __restrict__ lnkw, const float* __restrict__ lnkb,
                        u16* __restrict__ wqp, float* __restrict__ rwsQ, float* __restrict__ biasQ,
                        u16* __restrict__ wkvp, float* __restrict__ rwsKV, float* __restrict__ biasKV,
                        u16* __restrict__ wop) {
  int r = blockIdx.x * 256 + threadIdx.x;
  if (r < 384) {
    float rs = 0.f, bs = 0.f;
    for (int i = 0; i < 384; ++i) {
      float wp = wq[r * 384 + i] * lnqw[i];
      u16 h = f2b(wp);
      rs += b2f(h);
      bs += wq[r * 384 + i] * lnqb[i];
      wqp[r * 384 + i] = h;
    }
    rwsQ[r] = rs; biasQ[r] = bs;
  } else if (r < 640) {
    int o = r - 384;
    if (o < 192) {
      float rs = 0.f, bs = 0.f;
      for (int i = 0; i < 384; ++i) {
        float wp = wkv[o * 384 + i] * lnkw[i];
        u16 h = f2b(wp);
        rs += b2f(h);
        bs += wkv[o * 384 + i] * lnkb[i];
        wkvp[o * 384 + i] = h;
      }
      rwsKV[o] = rs; biasKV[o] = bs;
    } else {
      for (int i = 0; i < 384; ++i) wkvp[o * 384 + i] = 0;
      rwsKV[o] = 0.f; biasKV[o] = 0.f;
    }
  } else {
    int o = r - 640;
    for (int i = 0; i < 384; ++i) wop[o * 384 + i] = f2b(wo[o * 384 + i]);
  }
}

// ---------------------------------------------------------------------------
// k1: LN stats per pixel + transpose f32 [c][p] -> bf16 [p][c].
// ---------------------------------------------------------------------------
__global__ void k1_stats(const float* __restrict__ q, const float* __restrict__ k,
                         u16* __restrict__ qt, u16* __restrict__ kt,
                         float* __restrict__ muQ, float* __restrict__ sdQ,
                         float* __restrict__ muK, float* __restrict__ sdK) {
  int p = blockIdx.x * 256 + threadIdx.x;
  int b = blockIdx.y;
  int t = blockIdx.z;
  const float* src = t ? k : q;
  u16* dst = t ? kt : qt;
  float* mu = t ? muK : muQ;
  float* sd = t ? sdK : sdQ;

  size_t sbase = ((size_t)b * CDIM) * HW + p;
  uint4* dv = (uint4*)dst;
  size_t drow = ((size_t)(b * HW + p)) * 48;
  float sum = 0.f, sq = 0.f;
  for (int c8 = 0; c8 < 48; ++c8) {
    u32 w[4];
#pragma unroll
    for (int j = 0; j < 8; ++j) {
      float v = src[sbase + (size_t)(c8 * 8 + j) * HW];
      sum += v; sq += v * v;
      u16 h = f2b(v);
      if (j & 1) w[j >> 1] |= ((u32)h) << 16; else w[j >> 1] = (u32)h;
    }
    dv[drow + c8] = make_uint4(w[0], w[1], w[2], w[3]);
  }
  float m = sum * (1.f / 384.f);
  float var = sq * (1.f / 384.f) - m * m;
  int idx = b * HW + p;
  mu[idx] = m;
  sd[idx] = rsqrtf(var + 1e-5f);
}

// ---------------------------------------------------------------------------
// BT-GEMM: D[o][p] = sum_k A[o][k] * Bt[p][k], K=384.
// ---------------------------------------------------------------------------
template <int MODE>
__global__ __launch_bounds__(256) void gemm_bt(const u16* __restrict__ A,
                                               const u16* __restrict__ Bt,
                                               const float* __restrict__ rowsum,
                                               const float* __restrict__ bias,
                                               const float* __restrict__ mu,
                                               const float* __restrict__ rstd,
                                               void* __restrict__ outv, int M) {
  int b = blockIdx.z, ot = blockIdx.y, pt = blockIdx.x;
  int tid = threadIdx.x;
  int w = tid >> 6, l = tid & 63;
  int wm = w >> 1, wn = w & 1;
  int lr = l & 15, lg = l >> 4;

  f32x4 acc[4][4] = {};
  int arow0 = ot * 128 + wm * 64 + lr;
  size_t brow0 = (size_t)(b * HW + pt * 128 + wn * 64 + lr);

  for (int ks = 0; ks < 12; ++ks) {
    int ko = ks * 32 + lg * 8;
    s16x8 a[4], bb[4];
#pragma unroll
    for (int mf = 0; mf < 4; ++mf)
      a[mf] = *(const s16x8*)(A + (size_t)(arow0 + mf * 16) * 384 + ko);
#pragma unroll
    for (int nf = 0; nf < 4; ++nf)
      bb[nf] = *(const s16x8*)(Bt + (brow0 + nf * 16) * 384 + ko);
#pragma unroll
    for (int mf = 0; mf < 4; ++mf)
#pragma unroll
      for (int nf = 0; nf < 4; ++nf)
        acc[mf][nf] = __builtin_amdgcn_mfma_f32_16x16x32_bf16(a[mf], bb[nf], acc[mf][nf], 0, 0, 0);
  }

#pragma unroll
  for (int nf = 0; nf < 4; ++nf) {
    int p = pt * 128 + wn * 64 + nf * 16 + lr;
    float m_ = 0.f, s_ = 0.f;
    if (MODE == 0) { int pi = b * HW + p; m_ = mu[pi]; s_ = rstd[pi]; }
#pragma unroll
    for (int mf = 0; mf < 4; ++mf) {
#pragma unroll
      for (int r = 0; r < 4; ++r) {
        int o = ot * 128 + wm * 64 + mf * 16 + lg * 4 + r;
        if (MODE == 0) {
          if (o < M) {
            float v = s_ * (acc[mf][nf][r] - m_ * rowsum[o]) + bias[o];
            ((u16*)outv)[((size_t)(b * M + o)) * HW + p] = f2b(v);
          }
        } else {
          ((float*)outv)[((size_t)(b * CDIM + o)) * HW + p] = acc[mf][nf][r];
        }
      }
    }
  }
}

// ---------------------------------------------------------------------------
// k4: depthwise 3x3 (zero pad), LDS-staged plane + fused row l2-norm.
// grid (576, 8): x = channel (0..383 q, 384..575 kv), y = b. 256 thr.
// Block = one (b, channel) 128x128 plane = exactly one l2norm row.
// ---------------------------------------------------------------------------
__global__ __launch_bounds__(256) void k4_dw(const u16* __restrict__ qp, const u16* __restrict__ kvp,
                                             const float* __restrict__ wqdw, const float* __restrict__ wkvdw,
                                             u16* __restrict__ qd, u16* __restrict__ kvd,
                                             float* __restrict__ rnq, float* __restrict__ rnk) {
  __shared__ u16 plane[16384];     // 32 KB
  __shared__ float red[256];

  int c = blockIdx.x, b = blockIdx.y;
  int tid = threadIdx.x;
  const u16* in; u16* outb; const float* wp; int C;
  int isQ = (c < 384), cc = isQ ? c : c - 384;
  if (isQ) { in = qp; outb = qd; wp = wqdw + cc * 9; C = CDIM; }
  else     { in = kvp; outb = kvd; wp = wkvdw + cc * 9; C = KVC; }
  size_t base = ((size_t)(b * C + cc)) * HW;

  float w[9];
#pragma unroll
  for (int j = 0; j < 9; ++j) w[j] = wp[j];

  // stage plane: 2048 uint4, 8 per thread, coalesced
  const uint4* gsrc = (const uint4*)(in + base);
  uint4* lplane = (uint4*)plane;
#pragma unroll
  for (int i = 0; i < 8; ++i) lplane[tid + i * 256] = gsrc[tid + i * 256];
  __syncthreads();

  // compute: 2048 octets (8px each), 8 per thread
  uint4* gdst = (uint4*)(outb + base);
  float ns = 0.f;
#pragma unroll
  for (int it = 0; it < 8; ++it) {
    int idx = tid + it * 256;          // octet index
    int y = idx >> 4, ox = idx & 15;
    int x0 = ox * 8;

    float r[3][10];
#pragma unroll
    for (int rr = 0; rr < 3; ++rr) {
      int yy = y + rr - 1;
      if ((unsigned)yy < 128u) {
        int rbase = yy * 128 + x0;
        r[rr][0] = (x0 > 0) ? b2f(plane[rbase - 1]) : 0.f;
        uint4 v = *(const uint4*)&plane[rbase];
        u32 ws[4] = {v.x, v.y, v.z, v.w};
#pragma unroll
        for (int j = 0; j < 4; ++j) {
          r[rr][1 + 2 * j] = b2f((u16)(ws[j] & 0xffff));
          r[rr][2 + 2 * j] = b2f((u16)(ws[j] >> 16));
        }
        r[rr][9] = (x0 < 120) ? b2f(plane[rbase + 8]) : 0.f;
      } else {
#pragma unroll
        for (int j = 0; j < 10; ++j) r[rr][j] = 0.f;
      }
    }

    u32 packed[4];
#pragma unroll
    for (int j = 0; j < 8; ++j) {
      float a = 0.f;
#pragma unroll
      for (int rr = 0; rr < 3; ++rr)
#pragma unroll
        for (int dx = 0; dx < 3; ++dx)
          a += w[rr * 3 + dx] * r[rr][j + dx];
      u16 h = f2b(a);
      float hv = b2f(h);
      ns += hv * hv;
      if (j & 1) packed[j >> 1] |= ((u32)h) << 16; else packed[j >> 1] = (u32)h;
    }
    gdst[idx] = make_uint4(packed[0], packed[1], packed[2], packed[3]);
  }

  // fused l2-norm reduce (only q rows and k rows 0..95 need it)
  red[tid] = ns;
  __syncthreads();
  for (int st = 128; st > 0; st >>= 1) {
    if (tid < st) red[tid] += red[tid + st];
    __syncthreads();
  }
  if (tid == 0) {
    float n = sqrtf(red[0]);
    float inv = 1.f / fmaxf(n, 1e-12f);
    if (isQ) rnq[b * 384 + cc] = inv;
    else if (cc < 96) rnk[b * 96 + cc] = inv;
  }
}

// ---------------------------------------------------------------------------
// k5b: transpose v (kvd rows 96..191) -> vt [b][p][96] bf16. grid (64, 8).
// ---------------------------------------------------------------------------
__global__ void k5b_vt(const u16* __restrict__ kvd, u16* __restrict__ vt) {
  int p = blockIdx.x * 256 + threadIdx.x;
  int b = blockIdx.y;
  size_t sb = ((size_t)(b * KVC + 96)) * HW + p;
  uint4* dv = (uint4*)vt + ((size_t)(b * HW + p)) * 12;
  for (int j8 = 0; j8 < 12; ++j8) {
    u32 w[4];
#pragma unroll
    for (int j = 0; j < 8; ++j) {
      u16 h = kvd[sb + (size_t)(j8 * 8 + j) * HW];
      if (j & 1) w[j >> 1] |= ((u32)h) << 16; else w[j >> 1] = (u32)h;
    }
    dv[j8] = make_uint4(w[0], w[1], w[2], w[3]);
  }
}

// ---------------------------------------------------------------------------
// k6: split-K QK^T partials. grid (16, 8, 8): x = kchunk(1024), y = head, z = b.
// ---------------------------------------------------------------------------
__global__ __launch_bounds__(256) void k6_qk(const u16* __restrict__ qd,
                                             const u16* __restrict__ kvd,
                                             float* __restrict__ spart) {
  int kc = blockIdx.x, h = blockIdx.y, b = blockIdx.z;
  int tid = threadIdx.x;
  int w = tid >> 6, l = tid & 63, lr = l & 15, lg = l >> 4;
  int g = h >> 2;
  int p0 = kc * 1024 + w * 256;

  f32x4 acc[3][3] = {};
  size_t qbase = ((size_t)(b * CDIM + h * 48 + lr)) * HW;
  size_t kbase = ((size_t)(b * KVC + g * 48 + lr)) * HW;

  for (int ks = 0; ks < 8; ++ks) {
    int pp = p0 + ks * 32 + lg * 8;
    s16x8 a[3], bb[3];
#pragma unroll
    for (int mi = 0; mi < 3; ++mi) a[mi] = *(const s16x8*)(qd + qbase + (size_t)mi * 16 * HW + pp);
#pragma unroll
    for (int ni = 0; ni < 3; ++ni) bb[ni] = *(const s16x8*)(kvd + kbase + (size_t)ni * 16 * HW + pp);
#pragma unroll
    for (int mi = 0; mi < 3; ++mi)
#pragma unroll
      for (int ni = 0; ni < 3; ++ni)
        acc[mi][ni] = __builtin_amdgcn_mfma_f32_16x16x32_bf16(a[mi], bb[ni], acc[mi][ni], 0, 0, 0);
  }

  size_t sb = ((size_t)((((b * 8 + h) * 16) + kc) * 4 + w)) * 2304;
#pragma unroll
  for (int mi = 0; mi < 3; ++mi)
#pragma unroll
    for (int ni = 0; ni < 3; ++ni)
#pragma unroll
      for (int r = 0; r < 4; ++r) {
        int c = mi * 16 + lg * 4 + r, d = ni * 16 + lr;
        spart[sb + c * 48 + d] = acc[mi][ni][r];
      }
}

// ---------------------------------------------------------------------------
// k7: reduce partials + scale + softmax -> P~ [b][384][96] bf16.
// ---------------------------------------------------------------------------
__global__ void k7_sm(const float* __restrict__ spart, const float* __restrict__ temp,
                      const float* __restrict__ rnq, const float* __restrict__ rnk,
                      u16* __restrict__ ptil) {
  int h = blockIdx.x, b = blockIdx.y, tid = threadIdx.x;
  int g = h >> 2;
  __shared__ float S[2304];
  size_t base = ((size_t)((b * 8 + h) * 64)) * 2304;
  for (int e = tid; e < 2304; e += 64) {
    float s = 0.f;
    for (int j = 0; j < 64; ++j) s += spart[base + (size_t)j * 2304 + e];
    S[e] = s;
  }
  __syncthreads();
  if (tid < 48) {
    int c = tid;
    float sq = temp[h] * rnq[b * 384 + h * 48 + c];
    float mx = -1e30f;
    for (int d = 0; d < 48; ++d) {
      float v = S[c * 48 + d] * sq * rnk[b * 96 + g * 48 + d];
      mx = fmaxf(mx, v);
    }
    float sum = 0.f;
    for (int d = 0; d < 48; ++d) {
      float v = S[c * 48 + d] * sq * rnk[b * 96 + g * 48 + d];
      sum += __expf(v - mx);
    }
    float inv = 1.f / sum;
    u16* row = ptil + ((size_t)(b * 384 + h * 48 + c)) * 96;
    for (int dk = 0; dk < 96; ++dk) {
      int d = dk - g * 48;
      float pv = 0.f;
      if (d >= 0 && d < 48) {
        float v = S[c * 48 + d] * sq * rnk[b * 96 + g * 48 + d];
        pv = __expf(v - mx) * inv;
      }
      row[dk] = f2b(pv);
    }
  }
}

// ---------------------------------------------------------------------------
// k8: Yt[p][c] = sum_dk vt[p][dk] * P~[c][dk].  grid (128, 8), 512 thr.
// ---------------------------------------------------------------------------
__global__ __launch_bounds__(512) void k8_pv(const u16* __restrict__ vt,
                                             const u16* __restrict__ ptil,
                                             u16* __restrict__ yt) {
  int ptb = blockIdx.x, b = blockIdx.y;
  int tid = threadIdx.x;
  int w = tid >> 6, l = tid & 63, lr = l & 15, lg = l >> 4;
  int wm = w >> 2, wn = w & 3;

  f32x4 acc[4][6] = {};
  size_t arow0 = ((size_t)(b * HW + ptb * 128 + wm * 64 + lr)) * 96;
  size_t brow0 = ((size_t)(b * CDIM + wn * 96 + lr)) * 96;

  for (int ks = 0; ks < 3; ++ks) {
    int ko = ks * 32 + lg * 8;
    s16x8 a[4], bb[6];
#pragma unroll
    for (int mf = 0; mf < 4; ++mf) a[mf] = *(const s16x8*)(vt + arow0 + (size_t)mf * 16 * 96 + ko);
#pragma unroll
    for (int nf = 0; nf < 6; ++nf) bb[nf] = *(const s16x8*)(ptil + brow0 + (size_t)nf * 16 * 96 + ko);
#pragma unroll
    for (int mf = 0; mf < 4; ++mf)
#pragma unroll
      for (int nf = 0; nf < 6; ++nf)
        acc[mf][nf] = __builtin_amdgcn_mfma_f32_16x16x32_bf16(a[mf], bb[nf], acc[mf][nf], 0, 0, 0);
  }

#pragma unroll
  for (int mf = 0; mf < 4; ++mf)
#pragma unroll
    for (int nf = 0; nf < 6; ++nf)
#pragma unroll
      for (int r = 0; r < 4; ++r) {
        int p = ptb * 128 + wm * 64 + mf * 16 + lg * 4 + r;
        int c = wn * 96 + nf * 16 + lr;
        yt[((size_t)(b * HW + p)) * 384 + c] = f2b(acc[mf][nf][r]);
      }
}

// ---------------------------------------------------------------------------
extern "C" void kernel_launch(void* const* d_in, const int* in_sizes, int n_in,
                              void* d_out, int out_size, void* d_ws, size_t ws_size,
                              hipStream_t stream) {
  const float* q    = (const float*)d_in[0];
  const float* k    = (const float*)d_in[1];
  const float* w_q  = (const float*)d_in[2];
  const float* w_kv = (const float*)d_in[3];
  const float* w_qd = (const float*)d_in[4];
  const float* w_kd = (const float*)d_in[5];
  const float* w_o  = (const float*)d_in[6];
  const float* temp = (const float*)d_in[7];
  const float* lnqw = (const float*)d_in[8];
  const float* lnqb = (const float*)d_in[9];
  const float* lnkw = (const float*)d_in[10];
  const float* lnkb = (const float*)d_in[11];
  float* out = (float*)d_out;

  char* ws = (char*)d_ws;
  size_t off = 0;
  auto alloc = [&](size_t bytes) -> void* {
    void* p = ws + off;
    off += (bytes + 255) & ~(size_t)255;
    return p;
  };

  u16*   wqp   = (u16*)alloc(384 * 384 * 2);
  float* rwsQ  = (float*)alloc(384 * 4);
  float* biasQ = (float*)alloc(384 * 4);
  u16*   wkvp  = (u16*)alloc(256 * 384 * 2);   // padded to 256 rows
  float* rwsKV = (float*)alloc(256 * 4);
  float* biasKV= (float*)alloc(256 * 4);
  u16*   wop   = (u16*)alloc(384 * 384 * 2);
  float* muQ   = (float*)alloc((size_t)NB * HW * 4);
  float* sdQ   = (float*)alloc((size_t)NB * HW * 4);
  float* muK   = (float*)alloc((size_t)NB * HW * 4);
  float* sdK   = (float*)alloc((size_t)NB * HW * 4);
  u16*   qt    = (u16*)alloc((size_t)NB * HW * CDIM * 2);  // aliased as qd later
  u16*   kt    = (u16*)alloc((size_t)NB * HW * CDIM * 2);  // aliased as kvd later
  u16*   qp    = (u16*)alloc((size_t)NB * CDIM * HW * 2);  // aliased as yt later
  u16*   kvp   = (u16*)alloc((size_t)NB * KVC * HW * 2);
  u16*   vt    = (u16*)alloc((size_t)NB * HW * 96 * 2);
  float* spart = (float*)alloc((size_t)4096 * 2304 * 4);
  u16*   ptil  = (u16*)alloc((size_t)NB * CDIM * 96 * 2);
  float* rnq   = (float*)alloc((size_t)NB * 384 * 4);
  float* rnk   = (float*)alloc((size_t)NB * 96 * 4);

  // lifetime aliases (sequential stream => safe)
  u16* qd  = qt;    // qt dead after gemm q; qd written by k4
  u16* kvd = kt;    // kt dead after gemm kv
  u16* yt  = qp;    // qp dead after k4

  k0_prep<<<4, 256, 0, stream>>>(w_q, w_kv, w_o, lnqw, lnqb, lnkw, lnkb,
                                 wqp, rwsQ, biasQ, wkvp, rwsKV, biasKV, wop);

  k1_stats<<<dim3(64, NB, 2), 256, 0, stream>>>(q, k, qt, kt, muQ, sdQ, muK, sdK);

  gemm_bt<0><<<dim3(128, 3, NB), 256, 0, stream>>>(wqp, qt, rwsQ, biasQ, muQ, sdQ, qp, 384);
  gemm_bt<0><<<dim3(128, 2, NB), 256, 0, stream>>>(wkvp, kt, rwsKV, biasKV, muK, sdK, kvp, 192);

  k4_dw<<<dim3(576, NB), 256, 0, stream>>>(qp, kvp, w_qd, w_kd, qd, kvd, rnq, rnk);

  k5b_vt<<<dim3(64, NB), 256, 0, stream>>>(kvd, vt);

  k6_qk<<<dim3(16, 8, NB), 256, 0, stream>>>(qd, kvd, spart);
  k7_sm<<<dim3(8, NB), 64, 0, stream>>>(spart, temp, rnq, rnk, ptil);

  k8_pv<<<dim3(128, NB), 512, 0, stream>>>(vt, ptil, yt);

  gemm_bt<1><<<dim3(128, 3, NB), 256, 0, stream>>>(wop, yt, nullptr, nullptr, nullptr, nullptr, out, 384);
}